// Round 1
// baseline (425.606 us; speedup 1.0000x reference)
//
#include <hip/hip_runtime.h>

#define NRES 512
#define NN   (NRES * NRES)
#define CZ   128

typedef __attribute__((ext_vector_type(8))) short bf16x8;  // 8 bf16 = 4 VGPRs (MFMA A/B frag)
typedef __attribute__((ext_vector_type(4))) short s16x4;   // 8-byte packed store
typedef __attribute__((ext_vector_type(4))) float f32x4;   // MFMA C/D frag

static __device__ __forceinline__ short f2bf(float f) {
  union { float f; unsigned u; } v; v.f = f;
  unsigned r = v.u + 0x7fffu + ((v.u >> 16) & 1u);  // round-nearest-even
  return (short)(r >> 16);
}

static __device__ __forceinline__ void gload_lds16(const void* g, void* l) {
  // async global->LDS, 16B/lane; LDS dest is wave-uniform base + lane*16
  __builtin_amdgcn_global_load_lds(
      (__attribute__((address_space(1))) const void*)g,
      (__attribute__((address_space(3))) void*)l, 16, 0, 0);
}

// ---------------------------------------------------------------------------
// K0: weights -> bf16, transposed to MFMA B-operand layout.
// w_cat_t[col][z] = col<128 ? a_w[z][col] : b_w[z][col-128]   (256x128)
// w_out_t[z][c]   = out_w[c][z]                               (128x128)
// ---------------------------------------------------------------------------
__global__ __launch_bounds__(256) void k_prep(const float* __restrict__ a_w,
                                              const float* __restrict__ b_w,
                                              const float* __restrict__ out_w,
                                              short* __restrict__ w_cat_t,
                                              short* __restrict__ w_out_t) {
  int idx = blockIdx.x * 256 + threadIdx.x;
  if (idx < 256 * 128) {
    int cc = idx >> 7, zz = idx & 127;
    float v = (cc < 128) ? a_w[zz * 128 + cc] : b_w[zz * 128 + (cc - 128)];
    w_cat_t[idx] = f2bf(v);
  } else if (idx < 256 * 128 + 128 * 128) {
    int i2 = idx - 256 * 128;
    int zz = i2 >> 7, cc = i2 & 127;
    w_out_t[i2] = f2bf(out_w[cc * 128 + zz]);
  }
}

// ---------------------------------------------------------------------------
// K1: LN + dual projection. 64 rows/block, MFMA [64x128]@[128x256].
// Writes a_t[c][r], b_t[c][r] (r = i*N+k flat, contiguous) as bf16.
// ---------------------------------------------------------------------------
__global__ __launch_bounds__(256) void k_lnproj(const float* __restrict__ z,
                                                const float* __restrict__ ln_w,
                                                const float* __restrict__ ln_b,
                                                const float* __restrict__ a_bias,
                                                const float* __restrict__ b_bias,
                                                const short* __restrict__ w_cat_t,
                                                short* __restrict__ a_t,
                                                short* __restrict__ b_t) {
  __shared__ float xs[64][129];       // +1 pad: conflict-light LN phase
  __shared__ short xb[64][136];       // +8 bf16 pad: even bank spread for b128 frag reads
  __shared__ float part[2][4][64];
  __shared__ float mean_s[64], rstd_s[64];
  __shared__ float lnw_s[128], lnb_s[128];

  const int tid = threadIdx.x;
  const int r0 = blockIdx.x * 64;

  if (tid < 128) { lnw_s[tid] = ln_w[tid]; lnb_s[tid] = ln_b[tid]; }

  // 64x128 z-tile is contiguous in global; flat float4 copy
  const float4* zg = (const float4*)(z + (size_t)r0 * CZ);
#pragma unroll
  for (int it = 0; it < 8; ++it) {
    int idx = tid + it * 256;  // 0..2047 float4s
    float4 v = zg[idx];
    int row = idx >> 5, c4 = (idx & 31) * 4;
    xs[row][c4] = v.x; xs[row][c4 + 1] = v.y; xs[row][c4 + 2] = v.z; xs[row][c4 + 3] = v.w;
  }
  __syncthreads();

  {
    int row = tid & 63, seg = tid >> 6;
    float s = 0.f, s2 = 0.f;
#pragma unroll
    for (int m = 0; m < 32; ++m) { float v = xs[row][seg * 32 + m]; s += v; s2 += v * v; }
    part[0][seg][row] = s; part[1][seg][row] = s2;
  }
  __syncthreads();
  if (tid < 64) {
    float s  = part[0][0][tid] + part[0][1][tid] + part[0][2][tid] + part[0][3][tid];
    float s2 = part[1][0][tid] + part[1][1][tid] + part[1][2][tid] + part[1][3][tid];
    float mu = s * (1.f / CZ);
    float var = s2 * (1.f / CZ) - mu * mu;
    mean_s[tid] = mu;
    rstd_s[tid] = rsqrtf(var + 1e-5f);
  }
  __syncthreads();
#pragma unroll
  for (int it = 0; it < 32; ++it) {
    int idx = tid + it * 256;  // 0..8191
    int row = idx >> 7, k = idx & 127;
    float v = (xs[row][k] - mean_s[row]) * rstd_s[row] * lnw_s[k] + lnb_s[k];
    xb[row][k] = f2bf(v);
  }
  __syncthreads();

  const int w = tid >> 6, l = tid & 63;
  const int q = l >> 4, n16 = l & 15;
  const f32x4 zf = {0.f, 0.f, 0.f, 0.f};
  f32x4 acc[4][4];
#pragma unroll
  for (int a = 0; a < 4; ++a)
#pragma unroll
    for (int b = 0; b < 4; ++b) acc[a][b] = zf;

#pragma unroll
  for (int kk = 0; kk < 4; ++kk) {
    bf16x8 af[4], bfv[4];
#pragma unroll
    for (int rt = 0; rt < 4; ++rt)
      af[rt] = *(const bf16x8*)&xb[rt * 16 + n16][kk * 32 + q * 8];
#pragma unroll
    for (int ct = 0; ct < 4; ++ct) {
      int col = w * 64 + ct * 16 + n16;   // 0..255 (a|b concat); weights are L1/L2-hot
      bfv[ct] = *(const bf16x8*)&w_cat_t[col * 128 + kk * 32 + q * 8];
    }
#pragma unroll
    for (int rt = 0; rt < 4; ++rt)
#pragma unroll
      for (int ct = 0; ct < 4; ++ct)
        acc[rt][ct] = __builtin_amdgcn_mfma_f32_16x16x32_bf16(af[rt], bfv[ct], acc[rt][ct], 0, 0, 0);
  }

  // epilogue: +bias, bf16, transposed store to [c][r] (4 consecutive r per lane -> 8B store)
#pragma unroll
  for (int ct = 0; ct < 4; ++ct) {
    int col = w * 64 + ct * 16 + n16;
    int ch = col & 127;
    short* dst = (col < 128) ? a_t : b_t;
    float bias = (col < 128) ? a_bias[ch] : b_bias[ch];
#pragma unroll
    for (int rt = 0; rt < 4; ++rt) {
      s16x4 pk;
#pragma unroll
      for (int rg = 0; rg < 4; ++rg) pk[rg] = f2bf(acc[rt][ct][rg] + bias);
      *(s16x4*)&dst[(size_t)ch * NN + r0 + rt * 16 + q * 4] = pk;
    }
  }
}

// ---------------------------------------------------------------------------
// K2: per-channel C_c = A_c * B_c^T, 128x128 tile, K=512 in 16 steps of 32.
// global_load_lds(16B) staging with XOR chunk swizzle on the global source.
// XCD-aware bid mapping: a channel's 16 tiles share one XCD (A+B = 1MB < 4MB L2).
// ---------------------------------------------------------------------------
__global__ __launch_bounds__(256) void k_einsum(const short* __restrict__ a_t,
                                                const short* __restrict__ b_t,
                                                short* __restrict__ u_bf) {
  __shared__ short As[128 * 32], Bs[128 * 32];

  const int bid = blockIdx.x;
  const int xcd = bid & 7;
  const int g = bid >> 3;
  const int c = (xcd << 4) | (g >> 4);     // 0..127
  const int t = g & 15;
  const int ti = t >> 2, tj = t & 3;

  const short* Ab = a_t + (size_t)c * NN + (size_t)(ti * 128) * NRES;
  const short* Bb = b_t + (size_t)c * NN + (size_t)(tj * 128) * NRES;

  const int tid = threadIdx.x, w = tid >> 6, l = tid & 63;
  const int q = l >> 4, n16 = l & 15;
  const int wr = w >> 1, wc = w & 1;

  const int srow0 = w * 32 + (l >> 2);           // rows this lane stages (and +16)
  const int slot = l & 3;                        // fixed LDS chunk slot (HW: base+16*lane)

  const f32x4 zf = {0.f, 0.f, 0.f, 0.f};
  f32x4 acc[4][4];
#pragma unroll
  for (int a = 0; a < 4; ++a)
#pragma unroll
    for (int b = 0; b < 4; ++b) acc[a][b] = zf;

  for (int kk = 0; kk < 16; ++kk) {
    const int k0 = kk * 32;
    __syncthreads();  // prev iteration's frag reads done before overwrite
    {
      int r1 = srow0, r2 = srow0 + 16;
      int g1 = slot ^ ((r1 >> 1) & 3);           // global chunk feeding LDS slot
      int g2 = slot ^ ((r2 >> 1) & 3);
      gload_lds16(Ab + (size_t)r1 * NRES + k0 + g1 * 8, &As[r1 * 32 + slot * 8]);
      gload_lds16(Ab + (size_t)r2 * NRES + k0 + g2 * 8, &As[r2 * 32 + slot * 8]);
      gload_lds16(Bb + (size_t)r1 * NRES + k0 + g1 * 8, &Bs[r1 * 32 + slot * 8]);
      gload_lds16(Bb + (size_t)r2 * NRES + k0 + g2 * 8, &Bs[r2 * 32 + slot * 8]);
    }
    __syncthreads();  // drains vmcnt (global_load_lds) per barrier semantics

    bf16x8 af[4], bfv[4];
#pragma unroll
    for (int rt = 0; rt < 4; ++rt) {
      int m = wr * 64 + rt * 16 + n16;
      af[rt] = *(const bf16x8*)&As[m * 32 + (q ^ ((m >> 1) & 3)) * 8];
    }
#pragma unroll
    for (int ct = 0; ct < 4; ++ct) {
      int n = wc * 64 + ct * 16 + n16;
      bfv[ct] = *(const bf16x8*)&Bs[n * 32 + (q ^ ((n >> 1) & 3)) * 8];
    }
#pragma unroll
    for (int rt = 0; rt < 4; ++rt)
#pragma unroll
      for (int ct = 0; ct < 4; ++ct)
        acc[rt][ct] = __builtin_amdgcn_mfma_f32_16x16x32_bf16(af[rt], bfv[ct], acc[rt][ct], 0, 0, 0);
  }

  // epilogue: u_bf[c][i][j] = u/sqrt(N) in bf16
  short* ub = u_bf + (size_t)c * NN + (size_t)(ti * 128) * NRES + tj * 128;
  const float s = 0.04419417382415922f;  // 1/sqrt(512)
#pragma unroll
  for (int rt = 0; rt < 4; ++rt)
#pragma unroll
    for (int ct = 0; ct < 4; ++ct) {
      int il = wr * 64 + rt * 16 + q * 4;
      int jl = wc * 64 + ct * 16 + n16;
#pragma unroll
      for (int rg = 0; rg < 4; ++rg)
        ub[(size_t)(il + rg) * NRES + jl] = f2bf(acc[rt][ct][rg] * s);
    }
}

// ---------------------------------------------------------------------------
// K3: out[m][z] = sum_c u_s[c][m] * out_w[c][z] + out_b[z], masked.
// 128 positions/block; LDS transpose [c][m] -> Ut[m][c]; single stage (K=128).
// ---------------------------------------------------------------------------
__global__ __launch_bounds__(256) void k_outproj(const short* __restrict__ u_bf,
                                                 const short* __restrict__ w_out_t,
                                                 const float* __restrict__ out_b,
                                                 const int* __restrict__ mask,
                                                 float* __restrict__ out) {
  __shared__ short Ut[128 * 136];  // [m][c], +8 pad

  const int m0 = blockIdx.x * 128;
  const int tid = threadIdx.x, w = tid >> 6, l = tid & 63;
  const int q = l >> 4, n16 = l & 15;
  const int wr = w >> 1, wc = w & 1;

  // stage: thread handles c-pair (2*(tid&63)) over 32 m (wave-id selects m-group)
  {
    const int c0 = (tid & 63) * 2;
    const int mg = w * 32;
    const short* g0 = u_bf + (size_t)c0 * NN + m0 + mg;
    const short* g1 = g0 + NN;
#pragma unroll
    for (int v = 0; v < 4; ++v) {
      bf16x8 x0 = *(const bf16x8*)(g0 + v * 8);
      bf16x8 x1 = *(const bf16x8*)(g1 + v * 8);
#pragma unroll
      for (int j = 0; j < 8; ++j) {
        int m = mg + v * 8 + j;
        int pk = ((int)(unsigned short)x1[j] << 16) | (unsigned short)x0[j];
        *(int*)&Ut[m * 136 + c0] = pk;
      }
    }
  }
  __syncthreads();

  const f32x4 zf = {0.f, 0.f, 0.f, 0.f};
  f32x4 acc[4][4];
#pragma unroll
  for (int a = 0; a < 4; ++a)
#pragma unroll
    for (int b = 0; b < 4; ++b) acc[a][b] = zf;

#pragma unroll
  for (int kk = 0; kk < 4; ++kk) {
    bf16x8 af[4], bfv[4];
#pragma unroll
    for (int rt = 0; rt < 4; ++rt) {
      int m = wr * 64 + rt * 16 + n16;
      af[rt] = *(const bf16x8*)&Ut[m * 136 + kk * 32 + q * 8];
    }
#pragma unroll
    for (int ct = 0; ct < 4; ++ct) {
      int zc = wc * 64 + ct * 16 + n16;
      bfv[ct] = *(const bf16x8*)&w_out_t[zc * 128 + kk * 32 + q * 8];
    }
#pragma unroll
    for (int rt = 0; rt < 4; ++rt)
#pragma unroll
      for (int ct = 0; ct < 4; ++ct)
        acc[rt][ct] = __builtin_amdgcn_mfma_f32_16x16x32_bf16(af[rt], bfv[ct], acc[rt][ct], 0, 0, 0);
  }

  const int i_blk = m0 >> 9;          // block's 128 positions share row i
  const int j0 = m0 & 511;
  const int mi = mask[i_blk];
#pragma unroll
  for (int ct = 0; ct < 4; ++ct) {
    int zc = wc * 64 + ct * 16 + n16;
    float bias = out_b[zc];
#pragma unroll
    for (int rt = 0; rt < 4; ++rt) {
      int mloc = wr * 64 + rt * 16 + q * 4;
#pragma unroll
      for (int rg = 0; rg < 4; ++rg) {
        int m = m0 + mloc + rg;
        int jj = j0 + mloc + rg;
        float val = acc[rt][ct][rg] + bias;
        if (!(mi != 0 && mask[jj] != 0)) val = 0.f;
        out[(size_t)m * CZ + zc] = val;
      }
    }
  }
}

// ---------------------------------------------------------------------------
extern "C" void kernel_launch(void* const* d_in, const int* in_sizes, int n_in,
                              void* d_out, int out_size, void* d_ws, size_t ws_size,
                              hipStream_t stream) {
  const float* z     = (const float*)d_in[0];
  const int*   mask  = (const int*)d_in[1];
  const float* ln_w  = (const float*)d_in[2];
  const float* ln_b  = (const float*)d_in[3];
  const float* a_w   = (const float*)d_in[4];
  const float* a_b   = (const float*)d_in[5];
  const float* b_w   = (const float*)d_in[6];
  const float* b_b   = (const float*)d_in[7];
  const float* out_w = (const float*)d_in[8];
  const float* out_b = (const float*)d_in[9];
  float* out = (float*)d_out;

  char* p = (char*)d_ws;
  short* w_cat_t = (short*)p; p += (size_t)256 * 128 * 2;
  short* w_out_t = (short*)p; p += (size_t)128 * 128 * 2;
  short* a_t  = (short*)p; p += (size_t)NN * 128 * 2;
  short* b_t  = (short*)p; p += (size_t)NN * 128 * 2;
  short* u_bf = (short*)p; p += (size_t)NN * 128 * 2;
  // total ws use: ~192.1 MiB

  hipLaunchKernelGGL(k_prep,    dim3(192),  dim3(256), 0, stream, a_w, b_w, out_w, w_cat_t, w_out_t);
  hipLaunchKernelGGL(k_lnproj,  dim3(4096), dim3(256), 0, stream, z, ln_w, ln_b, a_b, b_b, w_cat_t, a_t, b_t);
  hipLaunchKernelGGL(k_einsum,  dim3(2048), dim3(256), 0, stream, a_t, b_t, u_bf);
  hipLaunchKernelGGL(k_outproj, dim3(2048), dim3(256), 0, stream, u_bf, w_out_t, out_b, mask, out);
}

// Round 2
// 382.672 us; speedup vs baseline: 1.1122x; 1.1122x over previous
//
#include <hip/hip_runtime.h>

#define NRES 512
#define NN   (NRES * NRES)
#define CZ   128

typedef __attribute__((ext_vector_type(8))) short bf16x8;  // 8 bf16 = 4 VGPRs (MFMA A/B frag)
typedef __attribute__((ext_vector_type(4))) short s16x4;   // 8-byte packed store
typedef __attribute__((ext_vector_type(4))) float f32x4;   // MFMA C/D frag

static __device__ __forceinline__ short f2bf(float f) {
  union { float f; unsigned u; } v; v.f = f;
  unsigned r = v.u + 0x7fffu + ((v.u >> 16) & 1u);  // round-nearest-even
  return (short)(r >> 16);
}

static __device__ __forceinline__ void gload_lds16(const void* g, void* l) {
  // async global->LDS, 16B/lane; LDS dest is wave-uniform base + lane*16
  __builtin_amdgcn_global_load_lds(
      (__attribute__((address_space(1))) const void*)g,
      (__attribute__((address_space(3))) void*)l, 16, 0, 0);
}

// ---------------------------------------------------------------------------
// K0: weights -> bf16, transposed to MFMA B-operand layout.
// ---------------------------------------------------------------------------
__global__ __launch_bounds__(256) void k_prep(const float* __restrict__ a_w,
                                              const float* __restrict__ b_w,
                                              const float* __restrict__ out_w,
                                              short* __restrict__ w_cat_t,
                                              short* __restrict__ w_out_t) {
  int idx = blockIdx.x * 256 + threadIdx.x;
  if (idx < 256 * 128) {
    int cc = idx >> 7, zz = idx & 127;
    float v = (cc < 128) ? a_w[zz * 128 + cc] : b_w[zz * 128 + (cc - 128)];
    w_cat_t[idx] = f2bf(v);
  } else if (idx < 256 * 128 + 128 * 128) {
    int i2 = idx - 256 * 128;
    int zz = i2 >> 7, cc = i2 & 127;
    w_out_t[i2] = f2bf(out_w[cc * 128 + zz]);
  }
}

// ---------------------------------------------------------------------------
// K1: LN (registers + quad shuffle) + dual projection MFMA [64x128]@[128x256].
// One barrier total; LDS = 17.4 KB (just the bf16 A-tile).
// ---------------------------------------------------------------------------
__global__ __launch_bounds__(256, 3) void k_lnproj(const float* __restrict__ z,
                                                   const float* __restrict__ ln_w,
                                                   const float* __restrict__ ln_b,
                                                   const float* __restrict__ a_bias,
                                                   const float* __restrict__ b_bias,
                                                   const short* __restrict__ w_cat_t,
                                                   short* __restrict__ a_t,
                                                   short* __restrict__ b_t) {
  __shared__ short xb[64][136];  // +8 pad

  const int tid = threadIdx.x;
  const int r0 = blockIdx.x * 64;
  const int row = tid >> 2, seg = tid & 3;  // 4 threads per row (same wave quad)

  // ---- LN phase, fully in registers ----
  const float4* zg = (const float4*)(z + (size_t)r0 * CZ);
  float4 v[8];
#pragma unroll
  for (int it = 0; it < 8; ++it) v[it] = zg[row * 32 + seg + it * 4];  // k = seg*4 + it*16

  float s = 0.f, s2 = 0.f;
#pragma unroll
  for (int it = 0; it < 8; ++it) {
    s  += v[it].x + v[it].y + v[it].z + v[it].w;
    s2 += v[it].x * v[it].x + v[it].y * v[it].y + v[it].z * v[it].z + v[it].w * v[it].w;
  }
  s  += __shfl_xor(s, 1);  s  += __shfl_xor(s, 2);
  s2 += __shfl_xor(s2, 1); s2 += __shfl_xor(s2, 2);
  const float mu = s * (1.f / CZ);
  const float rstd = rsqrtf(s2 * (1.f / CZ) - mu * mu + 1e-5f);

  const float4* lw4 = (const float4*)ln_w;
  const float4* lb4 = (const float4*)ln_b;
#pragma unroll
  for (int it = 0; it < 8; ++it) {
    float4 wv = lw4[seg + it * 4], bv = lb4[seg + it * 4];
    s16x4 pk;
    pk[0] = f2bf((v[it].x - mu) * rstd * wv.x + bv.x);
    pk[1] = f2bf((v[it].y - mu) * rstd * wv.y + bv.y);
    pk[2] = f2bf((v[it].z - mu) * rstd * wv.z + bv.z);
    pk[3] = f2bf((v[it].w - mu) * rstd * wv.w + bv.w);
    *(s16x4*)&xb[row][seg * 4 + it * 16] = pk;
  }
  __syncthreads();

  // ---- MFMA phase: [64x128] @ [128x256] ----
  const int w = tid >> 6, l = tid & 63;
  const int q = l >> 4, n16 = l & 15;
  const f32x4 zf = {0.f, 0.f, 0.f, 0.f};
  f32x4 acc[4][4];
#pragma unroll
  for (int a = 0; a < 4; ++a)
#pragma unroll
    for (int b = 0; b < 4; ++b) acc[a][b] = zf;

#pragma unroll
  for (int kk = 0; kk < 4; ++kk) {
    bf16x8 af[4], bfv[4];
#pragma unroll
    for (int rt = 0; rt < 4; ++rt)
      af[rt] = *(const bf16x8*)&xb[rt * 16 + n16][kk * 32 + q * 8];
#pragma unroll
    for (int ct = 0; ct < 4; ++ct) {
      int col = w * 64 + ct * 16 + n16;   // 0..255 (a|b concat); weights are L1/L2-hot
      bfv[ct] = *(const bf16x8*)&w_cat_t[col * 128 + kk * 32 + q * 8];
    }
#pragma unroll
    for (int rt = 0; rt < 4; ++rt)
#pragma unroll
      for (int ct = 0; ct < 4; ++ct)
        acc[rt][ct] = __builtin_amdgcn_mfma_f32_16x16x32_bf16(af[rt], bfv[ct], acc[rt][ct], 0, 0, 0);
  }

  // epilogue: +bias, bf16, transposed store to [c][r] (4 consecutive r per lane -> 8B store)
#pragma unroll
  for (int ct = 0; ct < 4; ++ct) {
    int col = w * 64 + ct * 16 + n16;
    int ch = col & 127;
    short* dst = (col < 128) ? a_t : b_t;
    float bias = (col < 128) ? a_bias[ch] : b_bias[ch];
#pragma unroll
    for (int rt = 0; rt < 4; ++rt) {
      s16x4 pk;
#pragma unroll
      for (int rg = 0; rg < 4; ++rg) pk[rg] = f2bf(acc[rt][ct][rg] + bias);
      *(s16x4*)&dst[(size_t)ch * NN + r0 + rt * 16 + q * 4] = pk;
    }
  }
}

// ---------------------------------------------------------------------------
// K2: per-channel C_c = A_c * B_c^T, 128x128 tile, K=512 in 8 stages of BK=64.
// global_load_lds(16B) + XOR chunk swizzle; XCD-aware c grouping.
// ---------------------------------------------------------------------------
__global__ __launch_bounds__(256, 3) void k_einsum(const short* __restrict__ a_t,
                                                   const short* __restrict__ b_t,
                                                   short* __restrict__ u_bf) {
  __shared__ short As[128 * 64], Bs[128 * 64];

  const int bid = blockIdx.x;
  const int xcd = bid & 7;
  const int g = bid >> 3;
  const int c = (xcd << 4) | (g >> 4);     // 0..127
  const int t = g & 15;
  const int ti = t >> 2, tj = t & 3;

  const short* Ab = a_t + (size_t)c * NN + (size_t)(ti * 128) * NRES;
  const short* Bb = b_t + (size_t)c * NN + (size_t)(tj * 128) * NRES;

  const int tid = threadIdx.x, w = tid >> 6, l = tid & 63;
  const int q = l >> 4, n16 = l & 15;
  const int wr = w >> 1, wc = w & 1;

  const int srow = l >> 3;                 // row within 8-row staging group
  const int schk = l & 7;                  // LDS chunk slot (HW: base + lane*16)
  const int gchk = schk ^ srow;            // swizzled global source chunk

  const f32x4 zf = {0.f, 0.f, 0.f, 0.f};
  f32x4 acc[4][4];
#pragma unroll
  for (int a = 0; a < 4; ++a)
#pragma unroll
    for (int b = 0; b < 4; ++b) acc[a][b] = zf;

  for (int st = 0; st < 8; ++st) {
    const int k0 = st * 64;
    __syncthreads();  // prev stage's frag reads done before overwrite
#pragma unroll
    for (int i = 0; i < 4; ++i) {
      int r = w * 32 + i * 8 + srow;
      gload_lds16(Ab + (size_t)r * NRES + k0 + gchk * 8, &As[(w * 32 + i * 8) * 64 + l * 8]);
      gload_lds16(Bb + (size_t)r * NRES + k0 + gchk * 8, &Bs[(w * 32 + i * 8) * 64 + l * 8]);
    }
    __syncthreads();  // drains vmcnt per barrier semantics

#pragma unroll
    for (int kk = 0; kk < 2; ++kk) {
      bf16x8 af[4], bfv[4];
#pragma unroll
      for (int rt = 0; rt < 4; ++rt) {
        int m = wr * 64 + rt * 16 + n16;
        af[rt] = *(const bf16x8*)&As[m * 64 + ((kk * 4 + q) ^ (m & 7)) * 8];
      }
#pragma unroll
      for (int ct = 0; ct < 4; ++ct) {
        int n = wc * 64 + ct * 16 + n16;
        bfv[ct] = *(const bf16x8*)&Bs[n * 64 + ((kk * 4 + q) ^ (n & 7)) * 8];
      }
#pragma unroll
      for (int rt = 0; rt < 4; ++rt)
#pragma unroll
        for (int ct = 0; ct < 4; ++ct)
          acc[rt][ct] = __builtin_amdgcn_mfma_f32_16x16x32_bf16(af[rt], bfv[ct], acc[rt][ct], 0, 0, 0);
    }
  }

  // epilogue: u_bf[c][i][j] = u/sqrt(N) in bf16
  short* ub = u_bf + (size_t)c * NN + (size_t)(ti * 128) * NRES + tj * 128;
  const float s = 0.04419417382415922f;  // 1/sqrt(512)
#pragma unroll
  for (int rt = 0; rt < 4; ++rt)
#pragma unroll
    for (int ct = 0; ct < 4; ++ct) {
      int il = wr * 64 + rt * 16 + q * 4;
      int jl = wc * 64 + ct * 16 + n16;
#pragma unroll
      for (int rg = 0; rg < 4; ++rg)
        ub[(size_t)(il + rg) * NRES + jl] = f2bf(acc[rt][ct][rg] * s);
    }
}

// ---------------------------------------------------------------------------
// K3: out[m][z] = sum_c u[c][m] * out_w[c][z] + out_b[z], masked.
// A = w_out_t[z][c] (global, L1-hot). B = u[c][m] staged coalesced into
// Us[c][m] (stride 130: B-frag c-gather is 2-way/free). D = [z][m]: each lane
// holds 4 consecutive z -> float4 stores of out[m][z].
// ---------------------------------------------------------------------------
#define US_S 130
__global__ __launch_bounds__(256, 3) void k_outproj(const short* __restrict__ u_bf,
                                                    const short* __restrict__ w_out_t,
                                                    const float* __restrict__ out_b,
                                                    const int* __restrict__ mask,
                                                    float* __restrict__ out) {
  __shared__ short Us[128 * US_S];

  const int m0 = blockIdx.x * 128;
  const int tid = threadIdx.x, w = tid >> 6, l = tid & 63;
  const int q = l >> 4, n16 = l & 15;
  const int wz = w >> 1, wm = w & 1;

  // ---- coalesced staging: lanes along m, 4 c-rows per wave-instr ----
  {
    const int mseg = tid & 15;         // 16B chunk along m
    const int cb = tid >> 4;           // 0..15
#pragma unroll
    for (int it = 0; it < 8; ++it) {
      int cc = it * 16 + cb;
      bf16x8 vv = *(const bf16x8*)(u_bf + (size_t)cc * NN + m0 + mseg * 8);
      int base = cc * US_S + mseg * 8;
#pragma unroll
      for (int wi = 0; wi < 4; ++wi) {
        int pk = ((int)(unsigned short)vv[2 * wi + 1] << 16) | (unsigned short)vv[2 * wi];
        *(int*)&Us[base + 2 * wi] = pk;
      }
    }
  }
  __syncthreads();

  const f32x4 zf = {0.f, 0.f, 0.f, 0.f};
  f32x4 acc[4][4];  // [rt: z-sub][ct: m-sub]
#pragma unroll
  for (int a = 0; a < 4; ++a)
#pragma unroll
    for (int b = 0; b < 4; ++b) acc[a][b] = zf;

#pragma unroll
  for (int kk = 0; kk < 4; ++kk) {
    bf16x8 af[4];  // A[z][c] = w_out_t
#pragma unroll
    for (int rt = 0; rt < 4; ++rt) {
      int zz = wz * 64 + rt * 16 + n16;
      af[rt] = *(const bf16x8*)&w_out_t[zz * 128 + kk * 32 + q * 8];
    }
    bf16x8 bfv[4];  // B[c][m] from Us (8 x u16 gather, conflict-free)
#pragma unroll
    for (int ct = 0; ct < 4; ++ct) {
      int mm = wm * 64 + ct * 16 + n16;
      int c0 = kk * 32 + q * 8;
      bf16x8 tv;
#pragma unroll
      for (int j = 0; j < 8; ++j) tv[j] = Us[(c0 + j) * US_S + mm];
      bfv[ct] = tv;
    }
#pragma unroll
    for (int rt = 0; rt < 4; ++rt)
#pragma unroll
      for (int ct = 0; ct < 4; ++ct)
        acc[rt][ct] = __builtin_amdgcn_mfma_f32_16x16x32_bf16(af[rt], bfv[ct], acc[rt][ct], 0, 0, 0);
  }

  // ---- epilogue: D[z][m]; lane holds z0..z0+3 for column m -> float4 store ----
  const int i_blk = m0 >> 9;
  const int j0 = m0 & 511;
  const int mi = mask[i_blk];
#pragma unroll
  for (int ct = 0; ct < 4; ++ct) {
    int mm = wm * 64 + ct * 16 + n16;
    int on = (mi != 0) && (mask[j0 + mm] != 0);
#pragma unroll
    for (int rt = 0; rt < 4; ++rt) {
      int z0 = wz * 64 + rt * 16 + q * 4;
      float4 bias = *(const float4*)&out_b[z0];
      float4 r;
      r.x = on ? acc[rt][ct][0] + bias.x : 0.f;
      r.y = on ? acc[rt][ct][1] + bias.y : 0.f;
      r.z = on ? acc[rt][ct][2] + bias.z : 0.f;
      r.w = on ? acc[rt][ct][3] + bias.w : 0.f;
      *(float4*)&out[(size_t)(m0 + mm) * CZ + z0] = r;
    }
  }
}

// ---------------------------------------------------------------------------
extern "C" void kernel_launch(void* const* d_in, const int* in_sizes, int n_in,
                              void* d_out, int out_size, void* d_ws, size_t ws_size,
                              hipStream_t stream) {
  const float* z     = (const float*)d_in[0];
  const int*   mask  = (const int*)d_in[1];
  const float* ln_w  = (const float*)d_in[2];
  const float* ln_b  = (const float*)d_in[3];
  const float* a_w   = (const float*)d_in[4];
  const float* a_b   = (const float*)d_in[5];
  const float* b_w   = (const float*)d_in[6];
  const float* b_b   = (const float*)d_in[7];
  const float* out_w = (const float*)d_in[8];
  const float* out_b = (const float*)d_in[9];
  float* out = (float*)d_out;

  char* p = (char*)d_ws;
  short* w_cat_t = (short*)p; p += (size_t)256 * 128 * 2;
  short* w_out_t = (short*)p; p += (size_t)128 * 128 * 2;
  short* a_t  = (short*)p; p += (size_t)NN * 128 * 2;
  short* b_t  = (short*)p; p += (size_t)NN * 128 * 2;
  short* u_bf = (short*)p; p += (size_t)NN * 128 * 2;

  hipLaunchKernelGGL(k_prep,    dim3(192),  dim3(256), 0, stream, a_w, b_w, out_w, w_cat_t, w_out_t);
  hipLaunchKernelGGL(k_lnproj,  dim3(4096), dim3(256), 0, stream, z, ln_w, ln_b, a_b, b_b, w_cat_t, a_t, b_t);
  hipLaunchKernelGGL(k_einsum,  dim3(2048), dim3(256), 0, stream, a_t, b_t, u_bf);
  hipLaunchKernelGGL(k_outproj, dim3(2048), dim3(256), 0, stream, u_bf, w_out_t, out_b, mask, out);
}

// Round 3
// 375.117 us; speedup vs baseline: 1.1346x; 1.0201x over previous
//
#include <hip/hip_runtime.h>

#define NRES 512
#define NN   (NRES * NRES)
#define CZ   128

typedef __attribute__((ext_vector_type(8))) short bf16x8;  // 8 bf16 = 4 VGPRs (MFMA A/B frag)
typedef __attribute__((ext_vector_type(4))) short s16x4;   // 8-byte packed store
typedef __attribute__((ext_vector_type(4))) float f32x4;   // MFMA C/D frag

static __device__ __forceinline__ short f2bf(float f) {
  union { float f; unsigned u; } v; v.f = f;
  unsigned r = v.u + 0x7fffu + ((v.u >> 16) & 1u);  // round-nearest-even
  return (short)(r >> 16);
}

static __device__ __forceinline__ void gload_lds16(const void* g, void* l) {
  // async global->LDS, 16B/lane; LDS dest is wave-uniform base + lane*16
  __builtin_amdgcn_global_load_lds(
      (__attribute__((address_space(1))) const void*)g,
      (__attribute__((address_space(3))) void*)l, 16, 0, 0);
}

// ---------------------------------------------------------------------------
// K0: weights -> bf16, transposed to MFMA B-operand layout.
// ---------------------------------------------------------------------------
__global__ __launch_bounds__(256) void k_prep(const float* __restrict__ a_w,
                                              const float* __restrict__ b_w,
                                              const float* __restrict__ out_w,
                                              short* __restrict__ w_cat_t,
                                              short* __restrict__ w_out_t) {
  int idx = blockIdx.x * 256 + threadIdx.x;
  if (idx < 256 * 128) {
    int cc = idx >> 7, zz = idx & 127;
    float v = (cc < 128) ? a_w[zz * 128 + cc] : b_w[zz * 128 + (cc - 128)];
    w_cat_t[idx] = f2bf(v);
  } else if (idx < 256 * 128 + 128 * 128) {
    int i2 = idx - 256 * 128;
    int zz = i2 >> 7, cc = i2 & 127;
    w_out_t[i2] = f2bf(out_w[cc * 128 + zz]);
  }
}

// ---------------------------------------------------------------------------
// K1: LN (registers + quad shuffle) + dual projection MFMA [64x128]@[128x256].
// Epilogue: per-wave LDS transpose (reusing xb) -> coalesced 128B/channel
// global stores (8 dwordx4 instrs/wave instead of 16x 8B scatter).
// ---------------------------------------------------------------------------
__global__ __launch_bounds__(256, 3) void k_lnproj(const float* __restrict__ z,
                                                   const float* __restrict__ ln_w,
                                                   const float* __restrict__ ln_b,
                                                   const float* __restrict__ a_bias,
                                                   const float* __restrict__ b_bias,
                                                   const short* __restrict__ w_cat_t,
                                                   short* __restrict__ a_t,
                                                   short* __restrict__ b_t) {
  __shared__ short xb[64][136];  // +8 pad; reused as 4x per-wave transpose buffers

  const int tid = threadIdx.x;
  const int r0 = blockIdx.x * 64;
  const int row = tid >> 2, seg = tid & 3;  // 4 threads per row (same wave quad)

  // ---- LN phase, fully in registers ----
  const float4* zg = (const float4*)(z + (size_t)r0 * CZ);
  float4 v[8];
#pragma unroll
  for (int it = 0; it < 8; ++it) v[it] = zg[row * 32 + seg + it * 4];  // k = seg*4 + it*16

  float s = 0.f, s2 = 0.f;
#pragma unroll
  for (int it = 0; it < 8; ++it) {
    s  += v[it].x + v[it].y + v[it].z + v[it].w;
    s2 += v[it].x * v[it].x + v[it].y * v[it].y + v[it].z * v[it].z + v[it].w * v[it].w;
  }
  s  += __shfl_xor(s, 1);  s  += __shfl_xor(s, 2);
  s2 += __shfl_xor(s2, 1); s2 += __shfl_xor(s2, 2);
  const float mu = s * (1.f / CZ);
  const float rstd = rsqrtf(s2 * (1.f / CZ) - mu * mu + 1e-5f);

  const float4* lw4 = (const float4*)ln_w;
  const float4* lb4 = (const float4*)ln_b;
#pragma unroll
  for (int it = 0; it < 8; ++it) {
    float4 wv = lw4[seg + it * 4], bv = lb4[seg + it * 4];
    s16x4 pk;
    pk[0] = f2bf((v[it].x - mu) * rstd * wv.x + bv.x);
    pk[1] = f2bf((v[it].y - mu) * rstd * wv.y + bv.y);
    pk[2] = f2bf((v[it].z - mu) * rstd * wv.z + bv.z);
    pk[3] = f2bf((v[it].w - mu) * rstd * wv.w + bv.w);
    *(s16x4*)&xb[row][seg * 4 + it * 16] = pk;
  }
  __syncthreads();

  // ---- MFMA phase: [64x128] @ [128x256] ----
  const int w = tid >> 6, l = tid & 63;
  const int q = l >> 4, n16 = l & 15;
  const f32x4 zf = {0.f, 0.f, 0.f, 0.f};
  f32x4 acc[4][4];
#pragma unroll
  for (int a = 0; a < 4; ++a)
#pragma unroll
    for (int b = 0; b < 4; ++b) acc[a][b] = zf;

#pragma unroll
  for (int kk = 0; kk < 4; ++kk) {
    bf16x8 af[4], bfv[4];
#pragma unroll
    for (int rt = 0; rt < 4; ++rt)
      af[rt] = *(const bf16x8*)&xb[rt * 16 + n16][kk * 32 + q * 8];
#pragma unroll
    for (int ct = 0; ct < 4; ++ct) {
      int col = w * 64 + ct * 16 + n16;   // 0..255 (a|b concat); weights are L1/L2-hot
      bfv[ct] = *(const bf16x8*)&w_cat_t[col * 128 + kk * 32 + q * 8];
    }
#pragma unroll
    for (int rt = 0; rt < 4; ++rt)
#pragma unroll
      for (int ct = 0; ct < 4; ++ct)
        acc[rt][ct] = __builtin_amdgcn_mfma_f32_16x16x32_bf16(af[rt], bfv[ct], acc[rt][ct], 0, 0, 0);
  }

  // ---- epilogue: per-wave LDS transpose, then coalesced stores ----
  __syncthreads();  // all waves done reading xb; safe to reuse as transpose bufs
  short* tb = &xb[0][0] + w * (16 * 66);  // per-wave 16ch x (64+2) rows buffer
  // a_t/b_t are contiguous in ws: col>=128 lands in b_t automatically
#pragma unroll
  for (int ct = 0; ct < 4; ++ct) {
    const int col = w * 64 + ct * 16 + n16;
    const int ch = col & 127;
    const float bias = (col < 128) ? a_bias[ch] : b_bias[ch];
#pragma unroll
    for (int rt = 0; rt < 4; ++rt) {
      s16x4 pk;
#pragma unroll
      for (int rg = 0; rg < 4; ++rg) pk[rg] = f2bf(acc[rt][ct][rg] + bias);
      *(s16x4*)&tb[n16 * 66 + rt * 16 + q * 4] = pk;  // [ch16][r64+2]
    }
    // wave-synchronous: same-wave DS ops retire in order; read back coalesced
#pragma unroll
    for (int i = 0; i < 2; ++i) {
      int ch_l = i * 8 + (l >> 3);
      int rseg = l & 7;
      bf16x8 t = *(const bf16x8*)&tb[ch_l * 66 + rseg * 8];
      int colg = w * 64 + ct * 16 + ch_l;
      *(bf16x8*)&a_t[(size_t)colg * NN + r0 + rseg * 8] = t;  // 128B run per channel
    }
  }
}

// ---------------------------------------------------------------------------
// K2: per-channel C_c = A_c * B_c^T, 128x128 tile, K=512 in 8 stages of BK=64.
// MFMA operands swapped (D = [j][i]) so the epilogue can pack b64 into a
// 128x128 LDS tile (union over As/Bs, stride 134: <=2-way banks both phases),
// then store u with fully-coalesced dwordx4 (8 instrs/thread, 256B runs).
// ---------------------------------------------------------------------------
__global__ __launch_bounds__(256, 3) void k_einsum(const short* __restrict__ a_t,
                                                   const short* __restrict__ b_t,
                                                   short* __restrict__ u_bf) {
  __shared__ short smem[128 * 134];        // 34.3 KB; As/Bs live in first 32 KB
  short* As = smem;                        // [128][64]
  short* Bs = smem + 128 * 64;             // [128][64]

  const int bid = blockIdx.x;
  const int xcd = bid & 7;
  const int g = bid >> 3;
  const int c = (xcd << 4) | (g >> 4);     // 0..127; 16 consecutive blocks/XCD per channel
  const int t = g & 15;
  const int ti = t >> 2, tj = t & 3;

  const short* Ab = a_t + (size_t)c * NN + (size_t)(ti * 128) * NRES;
  const short* Bb = b_t + (size_t)c * NN + (size_t)(tj * 128) * NRES;

  const int tid = threadIdx.x, w = tid >> 6, l = tid & 63;
  const int q = l >> 4, n16 = l & 15;
  const int wr = w >> 1, wc = w & 1;

  const int srow = l >> 3;                 // row within 8-row staging group
  const int schk = l & 7;                  // LDS chunk slot (HW: base + lane*16)
  const int gchk = schk ^ srow;            // swizzled global source chunk

  const f32x4 zf = {0.f, 0.f, 0.f, 0.f};
  f32x4 acc[4][4];                         // [jt][it]
#pragma unroll
  for (int a = 0; a < 4; ++a)
#pragma unroll
    for (int b = 0; b < 4; ++b) acc[a][b] = zf;

  for (int st = 0; st < 8; ++st) {
    const int k0 = st * 64;
    __syncthreads();  // prev stage's frag reads done before overwrite
#pragma unroll
    for (int i = 0; i < 4; ++i) {
      int r = w * 32 + i * 8 + srow;
      gload_lds16(Ab + (size_t)r * NRES + k0 + gchk * 8, &As[(w * 32 + i * 8) * 64 + l * 8]);
      gload_lds16(Bb + (size_t)r * NRES + k0 + gchk * 8, &Bs[(w * 32 + i * 8) * 64 + l * 8]);
    }
    __syncthreads();  // drains vmcnt per barrier semantics

#pragma unroll
    for (int kk = 0; kk < 2; ++kk) {
      bf16x8 af[4], bfv[4];
#pragma unroll
      for (int it = 0; it < 4; ++it) {
        int m = wr * 64 + it * 16 + n16;
        af[it] = *(const bf16x8*)&As[m * 64 + ((kk * 4 + q) ^ (m & 7)) * 8];
      }
#pragma unroll
      for (int jt = 0; jt < 4; ++jt) {
        int n = wc * 64 + jt * 16 + n16;
        bfv[jt] = *(const bf16x8*)&Bs[n * 64 + ((kk * 4 + q) ^ (n & 7)) * 8];
      }
      // operands swapped: D[m=j][n=i] -> lane holds 4 consecutive j per i
#pragma unroll
      for (int jt = 0; jt < 4; ++jt)
#pragma unroll
        for (int it = 0; it < 4; ++it)
          acc[jt][it] = __builtin_amdgcn_mfma_f32_16x16x32_bf16(bfv[jt], af[it], acc[jt][it], 0, 0, 0);
    }
  }

  // ---- epilogue: acc -> LDS tile [i][j] (stride 134) -> coalesced stores ----
  __syncthreads();  // all MFMA LDS reads done; reuse smem as the u-tile
  const float sc = 0.04419417382415922f;  // 1/sqrt(512)
#pragma unroll
  for (int jt = 0; jt < 4; ++jt)
#pragma unroll
    for (int it = 0; it < 4; ++it) {
      s16x4 pk;
#pragma unroll
      for (int rg = 0; rg < 4; ++rg) pk[rg] = f2bf(acc[jt][it][rg] * sc);
      int il = wr * 64 + it * 16 + n16;          // column of D = i
      int jl = wc * 64 + jt * 16 + q * 4;        // row of D = j (4 consecutive)
      *(s16x4*)&smem[il * 134 + jl] = pk;        // b64, <=2-way banks
    }
  __syncthreads();

  short* ub = u_bf + (size_t)c * NN + (size_t)(ti * 128) * NRES + tj * 128;
#pragma unroll
  for (int vv = 0; vv < 8; ++vv) {
    int CH = vv * 256 + tid;                     // 0..2047
    int i = CH >> 4, js = CH & 15;
    bf16x8 tv = *(const bf16x8*)&smem[i * 134 + js * 8];
    *(bf16x8*)&ub[(size_t)i * NRES + js * 8] = tv;  // 256B contiguous runs
  }
}

// ---------------------------------------------------------------------------
// K3: out[m][z] = sum_c u[c][m] * out_w[c][z] + out_b[z], masked. (unchanged)
// ---------------------------------------------------------------------------
#define US_S 130
__global__ __launch_bounds__(256, 3) void k_outproj(const short* __restrict__ u_bf,
                                                    const short* __restrict__ w_out_t,
                                                    const float* __restrict__ out_b,
                                                    const int* __restrict__ mask,
                                                    float* __restrict__ out) {
  __shared__ short Us[128 * US_S];

  const int m0 = blockIdx.x * 128;
  const int tid = threadIdx.x, w = tid >> 6, l = tid & 63;
  const int q = l >> 4, n16 = l & 15;
  const int wz = w >> 1, wm = w & 1;

  // ---- coalesced staging: lanes along m, 4 c-rows per wave-instr ----
  {
    const int mseg = tid & 15;         // 16B chunk along m
    const int cb = tid >> 4;           // 0..15
#pragma unroll
    for (int it = 0; it < 8; ++it) {
      int cc = it * 16 + cb;
      bf16x8 vv = *(const bf16x8*)(u_bf + (size_t)cc * NN + m0 + mseg * 8);
      int base = cc * US_S + mseg * 8;
#pragma unroll
      for (int wi = 0; wi < 4; ++wi) {
        int pk = ((int)(unsigned short)vv[2 * wi + 1] << 16) | (unsigned short)vv[2 * wi];
        *(int*)&Us[base + 2 * wi] = pk;
      }
    }
  }
  __syncthreads();

  const f32x4 zf = {0.f, 0.f, 0.f, 0.f};
  f32x4 acc[4][4];  // [rt: z-sub][ct: m-sub]
#pragma unroll
  for (int a = 0; a < 4; ++a)
#pragma unroll
    for (int b = 0; b < 4; ++b) acc[a][b] = zf;

#pragma unroll
  for (int kk = 0; kk < 4; ++kk) {
    bf16x8 af[4];  // A[z][c] = w_out_t
#pragma unroll
    for (int rt = 0; rt < 4; ++rt) {
      int zz = wz * 64 + rt * 16 + n16;
      af[rt] = *(const bf16x8*)&w_out_t[zz * 128 + kk * 32 + q * 8];
    }
    bf16x8 bfv[4];  // B[c][m] from Us (8 x u16 gather, broadcast-friendly)
#pragma unroll
    for (int ct = 0; ct < 4; ++ct) {
      int mm = wm * 64 + ct * 16 + n16;
      int c0 = kk * 32 + q * 8;
      bf16x8 tv;
#pragma unroll
      for (int j = 0; j < 8; ++j) tv[j] = Us[(c0 + j) * US_S + mm];
      bfv[ct] = tv;
    }
#pragma unroll
    for (int rt = 0; rt < 4; ++rt)
#pragma unroll
      for (int ct = 0; ct < 4; ++ct)
        acc[rt][ct] = __builtin_amdgcn_mfma_f32_16x16x32_bf16(af[rt], bfv[ct], acc[rt][ct], 0, 0, 0);
  }

  // ---- epilogue: D[z][m]; lane holds z0..z0+3 for column m -> float4 store ----
  const int i_blk = m0 >> 9;
  const int j0 = m0 & 511;
  const int mi = mask[i_blk];
#pragma unroll
  for (int ct = 0; ct < 4; ++ct) {
    int mm = wm * 64 + ct * 16 + n16;
    int on = (mi != 0) && (mask[j0 + mm] != 0);
#pragma unroll
    for (int rt = 0; rt < 4; ++rt) {
      int z0 = wz * 64 + rt * 16 + q * 4;
      float4 bias = *(const float4*)&out_b[z0];
      float4 r;
      r.x = on ? acc[rt][ct][0] + bias.x : 0.f;
      r.y = on ? acc[rt][ct][1] + bias.y : 0.f;
      r.z = on ? acc[rt][ct][2] + bias.z : 0.f;
      r.w = on ? acc[rt][ct][3] + bias.w : 0.f;
      *(float4*)&out[(size_t)(m0 + mm) * CZ + z0] = r;
    }
  }
}

// ---------------------------------------------------------------------------
extern "C" void kernel_launch(void* const* d_in, const int* in_sizes, int n_in,
                              void* d_out, int out_size, void* d_ws, size_t ws_size,
                              hipStream_t stream) {
  const float* z     = (const float*)d_in[0];
  const int*   mask  = (const int*)d_in[1];
  const float* ln_w  = (const float*)d_in[2];
  const float* ln_b  = (const float*)d_in[3];
  const float* a_w   = (const float*)d_in[4];
  const float* a_b   = (const float*)d_in[5];
  const float* b_w   = (const float*)d_in[6];
  const float* b_b   = (const float*)d_in[7];
  const float* out_w = (const float*)d_in[8];
  const float* out_b = (const float*)d_in[9];
  float* out = (float*)d_out;

  char* p = (char*)d_ws;
  short* w_cat_t = (short*)p; p += (size_t)256 * 128 * 2;
  short* w_out_t = (short*)p; p += (size_t)128 * 128 * 2;
  short* a_t  = (short*)p; p += (size_t)NN * 128 * 2;   // b_t contiguous after a_t
  short* b_t  = (short*)p; p += (size_t)NN * 128 * 2;
  short* u_bf = (short*)p; p += (size_t)NN * 128 * 2;

  hipLaunchKernelGGL(k_prep,    dim3(192),  dim3(256), 0, stream, a_w, b_w, out_w, w_cat_t, w_out_t);
  hipLaunchKernelGGL(k_lnproj,  dim3(4096), dim3(256), 0, stream, z, ln_w, ln_b, a_b, b_b, w_cat_t, a_t, b_t);
  hipLaunchKernelGGL(k_einsum,  dim3(2048), dim3(256), 0, stream, a_t, b_t, u_bf);
  hipLaunchKernelGGL(k_outproj, dim3(2048), dim3(256), 0, stream, u_bf, w_out_t, out_b, mask, out);
}